// Round 7
// baseline (882.993 us; speedup 1.0000x reference)
//
#include <hip/hip_runtime.h>
#include <hip/hip_fp16.h>
#include <math.h>

#define NN 100000
#define NE 1000000
#define NR 1000
#define DD 100
#define HS 104      // fp16 row stride (halves): 208 B, 16B-aligned, 4 cache lines
#define FS2 208     // fused fp16 feature row: [enc0:104h | enc1:104h] = 416 B
#define OUTC 600
#define EPS 1e-12f
#define NBIN 64
#define RESCALE_THR 8.0f
#define NWCH (NN / 16)   // 6250 wave-chunks of 16 nodes; NN = 6250*16 exactly

struct __attribute__((aligned(16))) h8 { unsigned short u[8]; };

__device__ inline float h2f(unsigned short u) {
    __half_raw r; r.x = u; __half h = r; return __half2float(h);
}
__device__ inline unsigned short f2h(float f) {
    __half h = __float2half_rn(f); __half_raw r = h; return r.x;
}

__device__ inline float wave_sum(float v) {
#pragma unroll
    for (int o = 32; o > 0; o >>= 1) v += __shfl_down(v, o, 64);
    return __shfl(v, 0, 64);
}
__device__ inline float quad_sum(float v) {
    v += __shfl_xor(v, 1, 64);
    v += __shfl_xor(v, 2, 64);
    return v;
}

// row_ptr[n] = lower_bound(dst, n); dst sorted ascending. row_ptr[NN] = NE.
__global__ void k_rowptr(const int* __restrict__ dst, int* __restrict__ row_ptr,
                         int* __restrict__ ghist) {
    int n = blockIdx.x * blockDim.x + threadIdx.x;
    if (n < NBIN) ghist[n] = 0;
    if (n > NN) return;
    int lo = 0, hi = NE;
    while (lo < hi) {
        int mid = (lo + hi) >> 1;
        if (dst[mid] < n) lo = mid + 1; else hi = mid;
    }
    row_ptr[n] = lo;
}

// ---- degree counting sort: nodes of similar degree adjacent in perm.
__global__ void k_hist(const int* __restrict__ row_ptr, int* __restrict__ ghist) {
    __shared__ int lh[NBIN];
    int t = threadIdx.x;
    if (t < NBIN) lh[t] = 0;
    __syncthreads();
    int n = blockIdx.x * blockDim.x + t;
    if (n < NN) {
        int d = row_ptr[n + 1] - row_ptr[n];
        atomicAdd(&lh[min(d, NBIN - 1)], 1);
    }
    __syncthreads();
    if (t < NBIN && lh[t]) atomicAdd(&ghist[t], lh[t]);
}
// exclusive scan + zero the 3 work-stealing counters (runs every launch)
__global__ void k_scan(const int* __restrict__ ghist, int* __restrict__ goffs,
                       int* __restrict__ ctrs) {
    if (threadIdx.x == 0) {
        int s = 0;
        for (int i = 0; i < NBIN; ++i) { goffs[i] = s; s += ghist[i]; }
        ctrs[0] = 0; ctrs[1] = 0; ctrs[2] = 0;
    }
}
__global__ void k_scatter(const int* __restrict__ row_ptr, int* __restrict__ goffs,
                          int* __restrict__ perm) {
    __shared__ int lh[NBIN], base[NBIN];
    int t = threadIdx.x;
    if (t < NBIN) lh[t] = 0;
    __syncthreads();
    int n = blockIdx.x * blockDim.x + t;
    int bin = 0, rank = 0;
    if (n < NN) {
        int d = row_ptr[n + 1] - row_ptr[n];
        bin = min(d, NBIN - 1);
        rank = atomicAdd(&lh[bin], 1);
    }
    __syncthreads();
    if (t < NBIN && lh[t]) base[t] = atomicAdd(&goffs[t], lh[t]);
    __syncthreads();
    if (n < NN) perm[base[bin] + rank] = n;
}

// packed edges: src (17 bits) | erel (<<17). src<2^17, erel<2^10.
__global__ void k_pack(const int* __restrict__ src, const int* __restrict__ erel,
                       unsigned int* __restrict__ ep) {
    int e = blockIdx.x * blockDim.x + threadIdx.x;
    if (e >= NE) return;
    ep[e] = (unsigned int)src[e] | ((unsigned int)erel[e] << 17);
}

// rel_norm (f32) + rel_nh (fp16, linear halves, stride HS); one wave per relation
__global__ void k_relnorm(const float* __restrict__ rel_emb, float* __restrict__ rel_norm,
                          unsigned short* __restrict__ rel_nh) {
    int w = (blockIdx.x * blockDim.x + threadIdx.x) >> 6;
    int lane = threadIdx.x & 63;
    if (w >= NR) return;
    const float* r = rel_emb + w * DD;
    float v0 = r[lane];
    float v1 = (lane + 64 < DD) ? r[lane + 64] : 0.f;
    float ss = wave_sum(v0 * v0 + v1 * v1);
    float sc = 1.f / fmaxf(sqrtf(ss), EPS);
    float* o = rel_norm + w * DD;
    unsigned short* oh = rel_nh + (size_t)w * HS;
    o[lane] = v0 * sc;
    oh[lane] = f2h(v0 * sc);
    if (lane + 64 < DD) {
        o[lane + 64] = v1 * sc;
        oh[lane + 64] = f2h(v1 * sc);
    }
}

// rrP[r] = { <r,w_r(A)>, <r,w_r(B)>, <r,w_n(A)>, <r,w_n(B)> }
__global__ void k_relv2(const float* __restrict__ rel_norm,
                        const float* __restrict__ k3dA, const float* __restrict__ k3dB,
                        float4* __restrict__ rrP) {
    int w = (blockIdx.x * blockDim.x + threadIdx.x) >> 6;
    int lane = threadIdx.x & 63;
    if (w >= NR) return;
    const float* r = rel_norm + w * DD;
    float r0 = r[lane];
    float r1 = (lane + 64 < DD) ? r[lane + 64] : 0.f;
    float wrA0 = k3dA[2 * DD + lane], wnA0 = k3dA[DD + lane];
    float wrB0 = k3dB[2 * DD + lane], wnB0 = k3dB[DD + lane];
    float wrA1 = 0.f, wnA1 = 0.f, wrB1 = 0.f, wnB1 = 0.f;
    if (lane + 64 < DD) {
        wrA1 = k3dA[2 * DD + lane + 64]; wnA1 = k3dA[DD + lane + 64];
        wrB1 = k3dB[2 * DD + lane + 64]; wnB1 = k3dB[DD + lane + 64];
    }
    float rdA = wave_sum(r0 * wrA0 + r1 * wrA1);
    float rdB = wave_sum(r0 * wrB0 + r1 * wrB1);
    float rnA = wave_sum(r0 * wnA0 + r1 * wnA1);
    float rnB = wave_sum(r0 * wnB0 + r1 * wnB1);
    if (lane == 0) { float4 v = { rdA, rdB, rnA, rnB }; rrP[w] = v; }
}

// f32 row (stride DD) -> fp16 row (stride HS), linear dims; one quad per row
__global__ void k_tohalf(const float* __restrict__ s, unsigned short* __restrict__ d, int rows) {
    int gi = blockIdx.x * blockDim.x + threadIdx.x;
    int n = gi >> 2, sb = gi & 3;
    if (n >= rows) return;
    const float4* s4 = (const float4*)(s + (size_t)n * DD);
    unsigned short* dr = d + (size_t)n * HS;
#pragma unroll
    for (int j = 0; j < 3; ++j) {
        float4 a = s4[6 * sb + 2 * j];
        float4 b = s4[6 * sb + 2 * j + 1];
        h8 o;
        o.u[0] = f2h(a.x); o.u[1] = f2h(a.y); o.u[2] = f2h(a.z); o.u[3] = f2h(a.w);
        o.u[4] = f2h(b.x); o.u[5] = f2h(b.y); o.u[6] = f2h(b.z); o.u[7] = f2h(b.w);
        ((h8*)(dr + 24 * sb))[j] = o;
    }
    dr[96 + sb] = f2h(s[(size_t)n * DD + 96 + sb]);
}

// ---- lane mapping: quad-lane sb owns dims [24sb..24sb+23] (m=0..23) + tail 96+sb (m=24).
// ---- work-stealing: waves grab chunks of 16 sorted nodes, DESCENDING degree (LPT).

// Fused segment-mean for BOTH encoders — one NODE per quad, fp16 gather tables.
__global__ __launch_bounds__(256) void k_segmean2(
        const unsigned short* __restrict__ ent_h, const unsigned short* __restrict__ rel_eh,
        const unsigned int* __restrict__ ep,
        const int* __restrict__ row_ptr, const int* __restrict__ perm,
        const float* __restrict__ k3dA, const float* __restrict__ k3dB,
        float2* __restrict__ sdP, float2* __restrict__ ndP,
        unsigned short* __restrict__ fused_out,   // nullable
        float* __restrict__ out, int* __restrict__ ctr) {
    int lane = threadIdx.x & 63;
    int qi = lane >> 2, sb = lane & 3;
    for (;;) {
        int t;
        if (lane == 0) t = atomicAdd(ctr, 1);
        t = __shfl(t, 0, 64);
        if (t >= NWCH) break;
        int gi = (NWCH - 1 - t) * 16 + qi;
        int n = perm[gi];
        int beg = row_ptr[n], end = row_ptr[n + 1];
        float a0[25] = {}, a1[25] = {};
        for (int e = beg; e < end; ++e) {
            unsigned int v = ep[e];
            int s = v & 0x1FFFF;
            int r = v >> 17;
            const unsigned short* er = ent_h + (size_t)s * HS;
            const unsigned short* rr = rel_eh + (size_t)r * HS;
            const h8* e8 = (const h8*)(er + 24 * sb);
            const h8* r8 = (const h8*)(rr + 24 * sb);
            h8 xa = e8[0], xb = e8[1], xc = e8[2];
            h8 ya = r8[0], yb = r8[1], yc = r8[2];
#pragma unroll
            for (int m = 0; m < 8; ++m) {
                a0[m]      += h2f(xa.u[m]);
                a0[8 + m]  += h2f(xb.u[m]);
                a0[16 + m] += h2f(xc.u[m]);
                a1[m]      += h2f(ya.u[m]);
                a1[8 + m]  += h2f(yb.u[m]);
                a1[16 + m] += h2f(yc.u[m]);
            }
            a0[24] += h2f(er[96 + sb]);
            a1[24] += h2f(rr[96 + sb]);
        }
        float inv = 1.f / fmaxf((float)(end - beg), 1.f);
        float o0[25], o1[25];
#pragma unroll
        for (int m = 0; m < 25; ++m) { o0[m] = tanhf(a0[m] * inv); o1[m] = tanhf(a1[m] * inv); }
        if (fused_out) {
            unsigned short* fr = fused_out + (size_t)n * FS2;
#pragma unroll
            for (int j = 0; j < 3; ++j) {
                h8 x, y;
#pragma unroll
                for (int m = 0; m < 8; ++m) { x.u[m] = f2h(o0[8 * j + m]); y.u[m] = f2h(o1[8 * j + m]); }
                ((h8*)(fr + 24 * sb))[j] = x;
                ((h8*)(fr + 104 + 24 * sb))[j] = y;
            }
            fr[96 + sb] = f2h(o0[24]);
            fr[200 + sb] = f2h(o1[24]);
        }
        float* oc = out + (size_t)n * OUTC;
        float4* oc4 = (float4*)oc;
        float4* od4 = (float4*)(oc + 300);
#pragma unroll
        for (int k = 0; k < 6; ++k) {
            float4 v0 = { o0[4 * k], o0[4 * k + 1], o0[4 * k + 2], o0[4 * k + 3] };
            oc4[6 * sb + k] = v0;
            float4 u0 = { o1[4 * k], o1[4 * k + 1], o1[4 * k + 2], o1[4 * k + 3] };
            od4[6 * sb + k] = u0;
        }
        oc[96 + sb] = o0[24];
        oc[300 + 96 + sb] = o1[24];
        // fused layer-0 node dots, both encoders
        float sp0 = o0[24] * k3dA[96 + sb], np0 = o0[24] * k3dA[DD + 96 + sb];
        float sp1 = o1[24] * k3dB[96 + sb], np1 = o1[24] * k3dB[DD + 96 + sb];
        const float4* wA = (const float4*)k3dA;
        const float4* wAn = (const float4*)(k3dA + DD);
        const float4* wB = (const float4*)k3dB;
        const float4* wBn = (const float4*)(k3dB + DD);
#pragma unroll
        for (int k = 0; k < 6; ++k) {
            float4 ws = wA[6 * sb + k], wn = wAn[6 * sb + k];
            sp0 += o0[4 * k] * ws.x + o0[4 * k + 1] * ws.y + o0[4 * k + 2] * ws.z + o0[4 * k + 3] * ws.w;
            np0 += o0[4 * k] * wn.x + o0[4 * k + 1] * wn.y + o0[4 * k + 2] * wn.z + o0[4 * k + 3] * wn.w;
            float4 vs = wB[6 * sb + k], vn = wBn[6 * sb + k];
            sp1 += o1[4 * k] * vs.x + o1[4 * k + 1] * vs.y + o1[4 * k + 2] * vs.z + o1[4 * k + 3] * vs.w;
            np1 += o1[4 * k] * vn.x + o1[4 * k + 1] * vn.y + o1[4 * k + 2] * vn.z + o1[4 * k + 3] * vn.w;
        }
        sp0 = quad_sum(sp0); np0 = quad_sum(np0);
        sp1 = quad_sum(sp1); np1 = quad_sum(np1);
        if (sb == 0) {
            float2 sv = { sp0, sp1 }; sdP[n] = sv;
            float2 nv = { np0, np1 }; ndP[n] = nv;
        }
    }
}

// Fused layer for BOTH encoders — one NODE per quad, work-stealing, register acc,
// defer-max online softmax. SRC=0: fused fp16 rows; SRC=1: f32 rows from out.
template<int SRC>
__global__ __launch_bounds__(256) void k_layer2(
        const void* __restrict__ Fin,
        const unsigned short* __restrict__ rel_nh,
        const unsigned int* __restrict__ ep,
        const int* __restrict__ row_ptr, const int* __restrict__ perm,
        const float2* __restrict__ sdP, const float2* __restrict__ ndP,
        const float4* __restrict__ rrP,
        const float* __restrict__ k3dA_next, const float* __restrict__ k3dB_next, // nullable
        float2* __restrict__ sdP_o, float2* __restrict__ ndP_o,
        unsigned short* __restrict__ fused_out,   // nullable
        float* __restrict__ out, int ocol, int* __restrict__ ctr) {
    int lane = threadIdx.x & 63;
    int qi = lane >> 2, sb = lane & 3;
    for (;;) {
        int tk;
        if (lane == 0) tk = atomicAdd(ctr, 1);
        tk = __shfl(tk, 0, 64);
        if (tk >= NWCH) break;
        int gi = (NWCH - 1 - tk) * 16 + qi;
        int n = perm[gi];
        int beg = row_ptr[n], end = row_ptr[n + 1];
        float2 sd2 = sdP[n];
        float acc0[25] = {}, acc1[25] = {};
        float m0 = -INFINITY, l0 = 0.f, m1 = -INFINITY, l1 = 0.f;
        for (int e = beg; e < end; ++e) {
            unsigned int v = ep[e];
            int s = v & 0x1FFFF;
            int r = v >> 17;
            float2 nd2 = ndP[s];
            float4 rr = rrP[r];           // {rd0, rd1, rw0, rw1}
            float f0[25], f1[25], rv[25];
            if (SRC == 0) {
                const unsigned short* fr = (const unsigned short*)Fin + (size_t)s * FS2;
                const h8* p = (const h8*)(fr + 24 * sb);
                const h8* q = (const h8*)(fr + 104 + 24 * sb);
                h8 x0 = p[0], x1 = p[1], x2 = p[2];
                h8 y0 = q[0], y1 = q[1], y2 = q[2];
#pragma unroll
                for (int m = 0; m < 8; ++m) {
                    f0[m] = h2f(x0.u[m]); f0[8 + m] = h2f(x1.u[m]); f0[16 + m] = h2f(x2.u[m]);
                    f1[m] = h2f(y0.u[m]); f1[8 + m] = h2f(y1.u[m]); f1[16 + m] = h2f(y2.u[m]);
                }
                f0[24] = h2f(fr[96 + sb]);
                f1[24] = h2f(fr[200 + sb]);
            } else {
                const float* fr = (const float*)Fin + (size_t)s * OUTC;
                const float4* a4 = (const float4*)fr;
                const float4* b4 = (const float4*)(fr + 300);
#pragma unroll
                for (int k = 0; k < 6; ++k) {
                    float4 vv = a4[6 * sb + k];
                    f0[4 * k] = vv.x; f0[4 * k + 1] = vv.y; f0[4 * k + 2] = vv.z; f0[4 * k + 3] = vv.w;
                    float4 uu = b4[6 * sb + k];
                    f1[4 * k] = uu.x; f1[4 * k + 1] = uu.y; f1[4 * k + 2] = uu.z; f1[4 * k + 3] = uu.w;
                }
                f0[24] = fr[96 + sb];
                f1[24] = fr[300 + 96 + sb];
            }
            const unsigned short* rh = rel_nh + (size_t)r * HS;
            const h8* rp = (const h8*)(rh + 24 * sb);
            h8 z0 = rp[0], z1 = rp[1], z2 = rp[2];
#pragma unroll
            for (int m = 0; m < 8; ++m) {
                rv[m] = h2f(z0.u[m]); rv[8 + m] = h2f(z1.u[m]); rv[16 + m] = h2f(z2.u[m]);
            }
            rv[24] = h2f(rh[96 + sb]);
            float p0 = f0[24] * rv[24], p1 = f1[24] * rv[24];
#pragma unroll
            for (int m = 0; m < 24; ++m) { p0 += f0[m] * rv[m]; p1 += f1[m] * rv[m]; }
            p0 = quad_sum(p0);
            p1 = quad_sum(p1);
            float c0 = 2.f * p0, c1 = 2.f * p1;
            float lg0 = sd2.x + nd2.x - c0 * rr.z + rr.x;
            float lg1 = sd2.y + nd2.y - c1 * rr.w + rr.y;
            float w0, w1;
            if (lg0 > m0 + RESCALE_THR) {
                float sc = __expf(m0 - lg0);   // 0 on first edge
                l0 *= sc;
#pragma unroll
                for (int m = 0; m < 25; ++m) acc0[m] *= sc;
                m0 = lg0; w0 = 1.f;
            } else w0 = __expf(lg0 - m0);
            if (lg1 > m1 + RESCALE_THR) {
                float sc = __expf(m1 - lg1);
                l1 *= sc;
#pragma unroll
                for (int m = 0; m < 25; ++m) acc1[m] *= sc;
                m1 = lg1; w1 = 1.f;
            } else w1 = __expf(lg1 - m1);
            l0 += w0; l1 += w1;
            float wc0 = w0 * c0, wc1 = w1 * c1;
#pragma unroll
            for (int m = 0; m < 25; ++m) {
                acc0[m] += w0 * f0[m] - wc0 * rv[m];
                acc1[m] += w1 * f1[m] - wc1 * rv[m];
            }
        }
        float i0 = (end > beg) ? (1.f / l0) : 0.f;
        float i1 = (end > beg) ? (1.f / l1) : 0.f;
        float o0[25], o1[25];
#pragma unroll
        for (int m = 0; m < 25; ++m) { o0[m] = tanhf(acc0[m] * i0); o1[m] = tanhf(acc1[m] * i1); }
        if (fused_out) {
            unsigned short* fr = fused_out + (size_t)n * FS2;
#pragma unroll
            for (int j = 0; j < 3; ++j) {
                h8 x, y;
#pragma unroll
                for (int m = 0; m < 8; ++m) { x.u[m] = f2h(o0[8 * j + m]); y.u[m] = f2h(o1[8 * j + m]); }
                ((h8*)(fr + 24 * sb))[j] = x;
                ((h8*)(fr + 104 + 24 * sb))[j] = y;
            }
            fr[96 + sb] = f2h(o0[24]);
            fr[200 + sb] = f2h(o1[24]);
        }
        float* oc = out + (size_t)n * OUTC + ocol;
        float4* oc4 = (float4*)oc;
        float4* od4 = (float4*)(oc + 300);
#pragma unroll
        for (int k = 0; k < 6; ++k) {
            float4 vv = { o0[4 * k], o0[4 * k + 1], o0[4 * k + 2], o0[4 * k + 3] };
            oc4[6 * sb + k] = vv;
            float4 uu = { o1[4 * k], o1[4 * k + 1], o1[4 * k + 2], o1[4 * k + 3] };
            od4[6 * sb + k] = uu;
        }
        oc[96 + sb] = o0[24];
        oc[300 + 96 + sb] = o1[24];
        if (k3dA_next) {
            float sp0 = o0[24] * k3dA_next[96 + sb], np0 = o0[24] * k3dA_next[DD + 96 + sb];
            float sp1 = o1[24] * k3dB_next[96 + sb], np1 = o1[24] * k3dB_next[DD + 96 + sb];
            const float4* wA = (const float4*)k3dA_next;
            const float4* wAn = (const float4*)(k3dA_next + DD);
            const float4* wB = (const float4*)k3dB_next;
            const float4* wBn = (const float4*)(k3dB_next + DD);
#pragma unroll
            for (int k = 0; k < 6; ++k) {
                float4 ws = wA[6 * sb + k], wn = wAn[6 * sb + k];
                sp0 += o0[4 * k] * ws.x + o0[4 * k + 1] * ws.y + o0[4 * k + 2] * ws.z + o0[4 * k + 3] * ws.w;
                np0 += o0[4 * k] * wn.x + o0[4 * k + 1] * wn.y + o0[4 * k + 2] * wn.z + o0[4 * k + 3] * wn.w;
                float4 vs = wB[6 * sb + k], vn = wBn[6 * sb + k];
                sp1 += o1[4 * k] * vs.x + o1[4 * k + 1] * vs.y + o1[4 * k + 2] * vs.z + o1[4 * k + 3] * vs.w;
                np1 += o1[4 * k] * vn.x + o1[4 * k + 1] * vn.y + o1[4 * k + 2] * vn.z + o1[4 * k + 3] * vn.w;
            }
            sp0 = quad_sum(sp0); np0 = quad_sum(np0);
            sp1 = quad_sum(sp1); np1 = quad_sum(np1);
            if (sb == 0) {
                float2 sv = { sp0, sp1 }; sdP_o[n] = sv;
                float2 nv = { np0, np1 }; ndP_o[n] = nv;
            }
        }
    }
}

extern "C" void kernel_launch(void* const* d_in, const int* in_sizes, int n_in,
                              void* d_out, int out_size, void* d_ws, size_t ws_size,
                              hipStream_t stream) {
    const float* ent_emb = (const float*)d_in[0];
    const float* rel_emb = (const float*)d_in[1];
    const float* attn_e  = (const float*)d_in[2];
    const float* attn_r  = (const float*)d_in[3];
    const int*   src     = (const int*)d_in[4];
    const int*   dst     = (const int*)d_in[5];
    const int*   erel    = (const int*)d_in[6];
    float* out = (float*)d_out;

    char* ws = (char*)d_ws;
    auto al = [](size_t x) { return (x + 255) & ~(size_t)255; };
    size_t o = 0;
    auto take = [&](size_t bytes) -> void* { void* p = ws + o; o = al(o + bytes); return p; };

    int*    row_ptr = (int*)take((NN + 1) * sizeof(int));
    unsigned short* rel_nh = (unsigned short*)take((size_t)NR * HS * 2);
    float2* sdPA = (float2*)take(NN * sizeof(float2));
    float2* ndPA = (float2*)take(NN * sizeof(float2));
    float2* sdPB = (float2*)take(NN * sizeof(float2));
    float2* ndPB = (float2*)take(NN * sizeof(float2));
    float4* rrP0 = (float4*)take(NR * sizeof(float4));
    float4* rrP1 = (float4*)take(NR * sizeof(float4));
    int*    ghist = (int*)take(NBIN * sizeof(int));
    int*    goffs = (int*)take(NBIN * sizeof(int));
    int*    perm  = (int*)take(NN * sizeof(int));
    int*    ctrs  = (int*)take(3 * sizeof(int));
    unsigned int* ep = (unsigned int*)take((size_t)NE * 4);

    // Region plan. Lifetimes: {ent_h, rel_eh, rel_norm} die after k_segmean2 /
    // prologue; fusedB is born at L1 → they may alias (plan A).
    size_t tbl0 = o;                                   // ent_h
    size_t tbl1 = al(tbl0 + (size_t)NN * HS * 2);      // rel_eh
    size_t tbl2 = al(tbl1 + (size_t)NR * HS * 2);      // rel_norm (f32)
    size_t tblE = al(tbl2 + (size_t)NR * DD * 4);
    size_t fsz  = al((size_t)NN * FS2 * 2);            // 41.6 MB
    size_t tblSpan = tblE - tbl0;
    size_t fA_A = tbl0 + (fsz > tblSpan ? fsz : tblSpan);
    bool planA = (fA_A + fsz) <= ws_size;              // fusedB aliases tables
    size_t fA_off = planA ? fA_A : tblE;
    bool haveFA = planA || ((tblE + fsz) <= ws_size);

    unsigned short* ent_h  = (unsigned short*)(ws + tbl0);
    unsigned short* rel_eh = (unsigned short*)(ws + tbl1);
    float*          rel_norm = (float*)(ws + tbl2);
    unsigned short* fusedA = haveFA ? (unsigned short*)(ws + fA_off) : (unsigned short*)nullptr;
    unsigned short* fusedB = planA ? (unsigned short*)(ws + tbl0) : (unsigned short*)nullptr;

    hipLaunchKernelGGL(k_rowptr, dim3((NN + 256) / 256), dim3(256), 0, stream,
                       dst, row_ptr, ghist);
    hipLaunchKernelGGL(k_hist, dim3((NN + 255) / 256), dim3(256), 0, stream, row_ptr, ghist);
    hipLaunchKernelGGL(k_scan, dim3(1), dim3(64), 0, stream, ghist, goffs, ctrs);
    hipLaunchKernelGGL(k_scatter, dim3((NN + 255) / 256), dim3(256), 0, stream,
                       row_ptr, goffs, perm);
    hipLaunchKernelGGL(k_pack, dim3((NE + 255) / 256), dim3(256), 0, stream, src, erel, ep);
    hipLaunchKernelGGL(k_relnorm, dim3(NR * 64 / 256), dim3(256), 0, stream,
                       rel_emb, rel_norm, rel_nh);
    hipLaunchKernelGGL(k_relv2, dim3(NR * 64 / 256), dim3(256), 0, stream,
                       rel_norm, attn_e, attn_r, rrP0);
    hipLaunchKernelGGL(k_relv2, dim3(NR * 64 / 256), dim3(256), 0, stream,
                       rel_norm, attn_e + 300, attn_r + 300, rrP1);
    hipLaunchKernelGGL(k_tohalf, dim3((NN * 4 + 255) / 256), dim3(256), 0, stream,
                       ent_emb, ent_h, NN);
    hipLaunchKernelGGL(k_tohalf, dim3((NR * 4 + 255) / 256), dim3(256), 0, stream,
                       rel_emb, rel_eh, NR);

    // layer 0: fused segment-mean for both encoders (+ layer-0 dots)
    hipLaunchKernelGGL(k_segmean2, dim3(2048), dim3(256), 0, stream,
                       ent_h, rel_eh, ep, row_ptr, perm,
                       attn_e, attn_r, sdPA, ndPA, fusedA, out, ctrs + 0);

    // layer 1: writes out cols 100/400 (+ dots for layer 2)
    if (haveFA) {
        hipLaunchKernelGGL(HIP_KERNEL_NAME(k_layer2<0>), dim3(1024), dim3(256), 0, stream,
                           (const void*)fusedA, rel_nh, ep, row_ptr, perm,
                           sdPA, ndPA, rrP0, attn_e + 300, attn_r + 300,
                           sdPB, ndPB, fusedB, out, 100, ctrs + 1);
    } else {
        hipLaunchKernelGGL(HIP_KERNEL_NAME(k_layer2<1>), dim3(1024), dim3(256), 0, stream,
                           (const void*)out, rel_nh, ep, row_ptr, perm,
                           sdPA, ndPA, rrP0, attn_e + 300, attn_r + 300,
                           sdPB, ndPB, (unsigned short*)nullptr, out, 100, ctrs + 1);
    }

    // layer 2: writes out cols 200/500 (no dots)
    if (planA) {
        hipLaunchKernelGGL(HIP_KERNEL_NAME(k_layer2<0>), dim3(1024), dim3(256), 0, stream,
                           (const void*)fusedB, rel_nh, ep, row_ptr, perm,
                           sdPB, ndPB, rrP1, (const float*)nullptr, (const float*)nullptr,
                           sdPB, ndPB, (unsigned short*)nullptr, out, 200, ctrs + 2);
    } else {
        hipLaunchKernelGGL(HIP_KERNEL_NAME(k_layer2<1>), dim3(1024), dim3(256), 0, stream,
                           (const void*)(out + 100), rel_nh, ep, row_ptr, perm,
                           sdPB, ndPB, rrP1, (const float*)nullptr, (const float*)nullptr,
                           sdPB, ndPB, (unsigned short*)nullptr, out, 200, ctrs + 2);
    }
}

// Round 8
// 738.565 us; speedup vs baseline: 1.1956x; 1.1956x over previous
//
#include <hip/hip_runtime.h>
#include <hip/hip_fp16.h>
#include <math.h>

#define NN 100000
#define NE 1000000
#define NR 1000
#define DD 100
#define HS 104      // fp16 row stride (halves): 208 B, 16B-aligned, 4 cache lines
#define FS2 208     // fused fp16 feature row: [enc0:104h | enc1:104h] = 416 B
#define OUTC 600
#define EPS 1e-12f
#define NBIN 64
#define RESCALE_THR 8.0f
#define NWCH (NN / 16)        // 6250 chunks of 16 degree-sorted nodes
#define NPAIR (NWCH / 2)      // 3125 mirror pairs: wave w owns chunks {w, 6249-w}
#define GRID_HEAVY 782        // 782 blocks * 4 waves = 3128 >= NPAIR; ~3 blocks/CU resident

struct __attribute__((aligned(16))) h8 { unsigned short u[8]; };

__device__ inline float h2f(unsigned short u) {
    __half_raw r; r.x = u; __half h = r; return __half2float(h);
}
__device__ inline unsigned short f2h(float f) {
    __half h = __float2half_rn(f); __half_raw r = h; return r.x;
}

__device__ inline float wave_sum(float v) {
#pragma unroll
    for (int o = 32; o > 0; o >>= 1) v += __shfl_down(v, o, 64);
    return __shfl(v, 0, 64);
}
__device__ inline float quad_sum(float v) {
    v += __shfl_xor(v, 1, 64);
    v += __shfl_xor(v, 2, 64);
    return v;
}

// row_ptr[n] = lower_bound(dst, n); dst sorted ascending. row_ptr[NN] = NE.
__global__ void k_rowptr(const int* __restrict__ dst, int* __restrict__ row_ptr,
                         int* __restrict__ ghist) {
    int n = blockIdx.x * blockDim.x + threadIdx.x;
    if (n < NBIN) ghist[n] = 0;
    if (n > NN) return;
    int lo = 0, hi = NE;
    while (lo < hi) {
        int mid = (lo + hi) >> 1;
        if (dst[mid] < n) lo = mid + 1; else hi = mid;
    }
    row_ptr[n] = lo;
}

// ---- degree counting sort: nodes of similar degree adjacent in perm (ascending).
__global__ void k_hist(const int* __restrict__ row_ptr, int* __restrict__ ghist) {
    __shared__ int lh[NBIN];
    int t = threadIdx.x;
    if (t < NBIN) lh[t] = 0;
    __syncthreads();
    int n = blockIdx.x * blockDim.x + t;
    if (n < NN) {
        int d = row_ptr[n + 1] - row_ptr[n];
        atomicAdd(&lh[min(d, NBIN - 1)], 1);
    }
    __syncthreads();
    if (t < NBIN && lh[t]) atomicAdd(&ghist[t], lh[t]);
}
__global__ void k_scan(const int* __restrict__ ghist, int* __restrict__ goffs) {
    if (threadIdx.x == 0) {
        int s = 0;
        for (int i = 0; i < NBIN; ++i) { goffs[i] = s; s += ghist[i]; }
    }
}
__global__ void k_scatter(const int* __restrict__ row_ptr, int* __restrict__ goffs,
                          int* __restrict__ perm) {
    __shared__ int lh[NBIN], base[NBIN];
    int t = threadIdx.x;
    if (t < NBIN) lh[t] = 0;
    __syncthreads();
    int n = blockIdx.x * blockDim.x + t;
    int bin = 0, rank = 0;
    if (n < NN) {
        int d = row_ptr[n + 1] - row_ptr[n];
        bin = min(d, NBIN - 1);
        rank = atomicAdd(&lh[bin], 1);
    }
    __syncthreads();
    if (t < NBIN && lh[t]) base[t] = atomicAdd(&goffs[t], lh[t]);
    __syncthreads();
    if (n < NN) perm[base[bin] + rank] = n;
}

// packed edges: src (17 bits) | erel (<<17).
__global__ void k_pack(const int* __restrict__ src, const int* __restrict__ erel,
                       unsigned int* __restrict__ ep) {
    int e = blockIdx.x * blockDim.x + threadIdx.x;
    if (e >= NE) return;
    ep[e] = (unsigned int)src[e] | ((unsigned int)erel[e] << 17);
}

// rel_norm (f32) + rel_nh (fp16, linear halves, stride HS); one wave per relation
__global__ void k_relnorm(const float* __restrict__ rel_emb, float* __restrict__ rel_norm,
                          unsigned short* __restrict__ rel_nh) {
    int w = (blockIdx.x * blockDim.x + threadIdx.x) >> 6;
    int lane = threadIdx.x & 63;
    if (w >= NR) return;
    const float* r = rel_emb + w * DD;
    float v0 = r[lane];
    float v1 = (lane + 64 < DD) ? r[lane + 64] : 0.f;
    float ss = wave_sum(v0 * v0 + v1 * v1);
    float sc = 1.f / fmaxf(sqrtf(ss), EPS);
    float* o = rel_norm + w * DD;
    unsigned short* oh = rel_nh + (size_t)w * HS;
    o[lane] = v0 * sc;
    oh[lane] = f2h(v0 * sc);
    if (lane + 64 < DD) {
        o[lane + 64] = v1 * sc;
        oh[lane + 64] = f2h(v1 * sc);
    }
}

// rrP[r] = { <r,w_r(A)>, <r,w_r(B)>, <r,w_n(A)>, <r,w_n(B)> }
__global__ void k_relv2(const float* __restrict__ rel_norm,
                        const float* __restrict__ k3dA, const float* __restrict__ k3dB,
                        float4* __restrict__ rrP) {
    int w = (blockIdx.x * blockDim.x + threadIdx.x) >> 6;
    int lane = threadIdx.x & 63;
    if (w >= NR) return;
    const float* r = rel_norm + w * DD;
    float r0 = r[lane];
    float r1 = (lane + 64 < DD) ? r[lane + 64] : 0.f;
    float wrA0 = k3dA[2 * DD + lane], wnA0 = k3dA[DD + lane];
    float wrB0 = k3dB[2 * DD + lane], wnB0 = k3dB[DD + lane];
    float wrA1 = 0.f, wnA1 = 0.f, wrB1 = 0.f, wnB1 = 0.f;
    if (lane + 64 < DD) {
        wrA1 = k3dA[2 * DD + lane + 64]; wnA1 = k3dA[DD + lane + 64];
        wrB1 = k3dB[2 * DD + lane + 64]; wnB1 = k3dB[DD + lane + 64];
    }
    float rdA = wave_sum(r0 * wrA0 + r1 * wrA1);
    float rdB = wave_sum(r0 * wrB0 + r1 * wrB1);
    float rnA = wave_sum(r0 * wnA0 + r1 * wnA1);
    float rnB = wave_sum(r0 * wnB0 + r1 * wnB1);
    if (lane == 0) { float4 v = { rdA, rdB, rnA, rnB }; rrP[w] = v; }
}

// f32 row (stride DD) -> fp16 row (stride HS); one quad per row
__global__ void k_tohalf(const float* __restrict__ s, unsigned short* __restrict__ d, int rows) {
    int gi = blockIdx.x * blockDim.x + threadIdx.x;
    int n = gi >> 2, sb = gi & 3;
    if (n >= rows) return;
    const float4* s4 = (const float4*)(s + (size_t)n * DD);
    unsigned short* dr = d + (size_t)n * HS;
#pragma unroll
    for (int j = 0; j < 3; ++j) {
        float4 a = s4[6 * sb + 2 * j];
        float4 b = s4[6 * sb + 2 * j + 1];
        h8 o;
        o.u[0] = f2h(a.x); o.u[1] = f2h(a.y); o.u[2] = f2h(a.z); o.u[3] = f2h(a.w);
        o.u[4] = f2h(b.x); o.u[5] = f2h(b.y); o.u[6] = f2h(b.z); o.u[7] = f2h(b.w);
        ((h8*)(dr + 24 * sb))[j] = o;
    }
    dr[96 + sb] = f2h(s[(size_t)n * DD + 96 + sb]);
}

// ---- lane mapping: quad-lane sb owns dims [24sb..24sb+23] (m=0..23) + tail 96+sb (m=24).
// ---- schedule: wave w (w < NPAIR) statically owns chunks {w, NWCH-1-w} of the
//      ascending-degree-sorted perm — mirror pairing equalizes per-wave total
//      degree with ZERO atomics (the round-7 global counter serialized the kernel).

// Fused segment-mean for BOTH encoders — one NODE per quad, fp16 gather tables,
// 2-WAY EDGE UNROLL (doubles loads in flight per quad; plain sum so trivially legal).
__global__ __launch_bounds__(256) void k_segmean2(
        const unsigned short* __restrict__ ent_h, const unsigned short* __restrict__ rel_eh,
        const unsigned int* __restrict__ ep,
        const int* __restrict__ row_ptr, const int* __restrict__ perm,
        const float* __restrict__ k3dA, const float* __restrict__ k3dB,
        float2* __restrict__ sdP, float2* __restrict__ ndP,
        unsigned short* __restrict__ fused_out,   // nullable
        float* __restrict__ out) {
    int wv = (blockIdx.x * blockDim.x + threadIdx.x) >> 6;
    int lane = threadIdx.x & 63;
    int qi = lane >> 2, sb = lane & 3;
    if (wv >= NPAIR) return;
    for (int half = 0; half < 2; ++half) {
        int c = half ? (NWCH - 1 - wv) : wv;
        int n = perm[c * 16 + qi];
        int beg = row_ptr[n], end = row_ptr[n + 1];
        float a0[25] = {}, a1[25] = {};
        int e = beg;
        for (; e + 1 < end; e += 2) {
            unsigned int v0 = ep[e], v1 = ep[e + 1];
            int s0 = v0 & 0x1FFFF, r0 = v0 >> 17;
            int s1 = v1 & 0x1FFFF, r1 = v1 >> 17;
            const unsigned short* er0 = ent_h + (size_t)s0 * HS;
            const unsigned short* rr0 = rel_eh + (size_t)r0 * HS;
            const unsigned short* er1 = ent_h + (size_t)s1 * HS;
            const unsigned short* rr1 = rel_eh + (size_t)r1 * HS;
            const h8* pe0 = (const h8*)(er0 + 24 * sb);
            const h8* pr0 = (const h8*)(rr0 + 24 * sb);
            const h8* pe1 = (const h8*)(er1 + 24 * sb);
            const h8* pr1 = (const h8*)(rr1 + 24 * sb);
            h8 xa0 = pe0[0], xb0 = pe0[1], xc0 = pe0[2];
            h8 ya0 = pr0[0], yb0 = pr0[1], yc0 = pr0[2];
            h8 xa1 = pe1[0], xb1 = pe1[1], xc1 = pe1[2];
            h8 ya1 = pr1[0], yb1 = pr1[1], yc1 = pr1[2];
            unsigned short te0 = er0[96 + sb], tr0 = rr0[96 + sb];
            unsigned short te1 = er1[96 + sb], tr1 = rr1[96 + sb];
#pragma unroll
            for (int m = 0; m < 8; ++m) {
                a0[m]      += h2f(xa0.u[m]) + h2f(xa1.u[m]);
                a0[8 + m]  += h2f(xb0.u[m]) + h2f(xb1.u[m]);
                a0[16 + m] += h2f(xc0.u[m]) + h2f(xc1.u[m]);
                a1[m]      += h2f(ya0.u[m]) + h2f(ya1.u[m]);
                a1[8 + m]  += h2f(yb0.u[m]) + h2f(yb1.u[m]);
                a1[16 + m] += h2f(yc0.u[m]) + h2f(yc1.u[m]);
            }
            a0[24] += h2f(te0) + h2f(te1);
            a1[24] += h2f(tr0) + h2f(tr1);
        }
        if (e < end) {
            unsigned int v = ep[e];
            int s = v & 0x1FFFF;
            int r = v >> 17;
            const unsigned short* er = ent_h + (size_t)s * HS;
            const unsigned short* rr = rel_eh + (size_t)r * HS;
            const h8* e8 = (const h8*)(er + 24 * sb);
            const h8* r8 = (const h8*)(rr + 24 * sb);
            h8 xa = e8[0], xb = e8[1], xc = e8[2];
            h8 ya = r8[0], yb = r8[1], yc = r8[2];
#pragma unroll
            for (int m = 0; m < 8; ++m) {
                a0[m]      += h2f(xa.u[m]);
                a0[8 + m]  += h2f(xb.u[m]);
                a0[16 + m] += h2f(xc.u[m]);
                a1[m]      += h2f(ya.u[m]);
                a1[8 + m]  += h2f(yb.u[m]);
                a1[16 + m] += h2f(yc.u[m]);
            }
            a0[24] += h2f(er[96 + sb]);
            a1[24] += h2f(rr[96 + sb]);
        }
        float inv = 1.f / fmaxf((float)(end - beg), 1.f);
        float o0[25], o1[25];
#pragma unroll
        for (int m = 0; m < 25; ++m) { o0[m] = tanhf(a0[m] * inv); o1[m] = tanhf(a1[m] * inv); }
        if (fused_out) {
            unsigned short* fr = fused_out + (size_t)n * FS2;
#pragma unroll
            for (int j = 0; j < 3; ++j) {
                h8 x, y;
#pragma unroll
                for (int m = 0; m < 8; ++m) { x.u[m] = f2h(o0[8 * j + m]); y.u[m] = f2h(o1[8 * j + m]); }
                ((h8*)(fr + 24 * sb))[j] = x;
                ((h8*)(fr + 104 + 24 * sb))[j] = y;
            }
            fr[96 + sb] = f2h(o0[24]);
            fr[200 + sb] = f2h(o1[24]);
        }
        float* oc = out + (size_t)n * OUTC;
        float4* oc4 = (float4*)oc;
        float4* od4 = (float4*)(oc + 300);
#pragma unroll
        for (int k = 0; k < 6; ++k) {
            float4 v0 = { o0[4 * k], o0[4 * k + 1], o0[4 * k + 2], o0[4 * k + 3] };
            oc4[6 * sb + k] = v0;
            float4 u0 = { o1[4 * k], o1[4 * k + 1], o1[4 * k + 2], o1[4 * k + 3] };
            od4[6 * sb + k] = u0;
        }
        oc[96 + sb] = o0[24];
        oc[300 + 96 + sb] = o1[24];
        // fused layer-0 node dots, both encoders
        float sp0 = o0[24] * k3dA[96 + sb], np0 = o0[24] * k3dA[DD + 96 + sb];
        float sp1 = o1[24] * k3dB[96 + sb], np1 = o1[24] * k3dB[DD + 96 + sb];
        const float4* wA = (const float4*)k3dA;
        const float4* wAn = (const float4*)(k3dA + DD);
        const float4* wB = (const float4*)k3dB;
        const float4* wBn = (const float4*)(k3dB + DD);
#pragma unroll
        for (int k = 0; k < 6; ++k) {
            float4 ws = wA[6 * sb + k], wn = wAn[6 * sb + k];
            sp0 += o0[4 * k] * ws.x + o0[4 * k + 1] * ws.y + o0[4 * k + 2] * ws.z + o0[4 * k + 3] * ws.w;
            np0 += o0[4 * k] * wn.x + o0[4 * k + 1] * wn.y + o0[4 * k + 2] * wn.z + o0[4 * k + 3] * wn.w;
            float4 vs = wB[6 * sb + k], vn = wBn[6 * sb + k];
            sp1 += o1[4 * k] * vs.x + o1[4 * k + 1] * vs.y + o1[4 * k + 2] * vs.z + o1[4 * k + 3] * vs.w;
            np1 += o1[4 * k] * vn.x + o1[4 * k + 1] * vn.y + o1[4 * k + 2] * vn.z + o1[4 * k + 3] * vn.w;
        }
        sp0 = quad_sum(sp0); np0 = quad_sum(np0);
        sp1 = quad_sum(sp1); np1 = quad_sum(np1);
        if (sb == 0) {
            float2 sv = { sp0, sp1 }; sdP[n] = sv;
            float2 nv = { np0, np1 }; ndP[n] = nv;
        }
    }
}

// Fused layer for BOTH encoders — one NODE per quad, mirror-paired static
// schedule, register acc, defer-max online softmax. SRC=0: fused fp16 rows;
// SRC=1: f32 rows from out.
template<int SRC>
__global__ __launch_bounds__(256) void k_layer2(
        const void* __restrict__ Fin,
        const unsigned short* __restrict__ rel_nh,
        const unsigned int* __restrict__ ep,
        const int* __restrict__ row_ptr, const int* __restrict__ perm,
        const float2* __restrict__ sdP, const float2* __restrict__ ndP,
        const float4* __restrict__ rrP,
        const float* __restrict__ k3dA_next, const float* __restrict__ k3dB_next, // nullable
        float2* __restrict__ sdP_o, float2* __restrict__ ndP_o,
        unsigned short* __restrict__ fused_out,   // nullable
        float* __restrict__ out, int ocol) {
    int wv = (blockIdx.x * blockDim.x + threadIdx.x) >> 6;
    int lane = threadIdx.x & 63;
    int qi = lane >> 2, sb = lane & 3;
    if (wv >= NPAIR) return;
    for (int half = 0; half < 2; ++half) {
        int c = half ? (NWCH - 1 - wv) : wv;
        int n = perm[c * 16 + qi];
        int beg = row_ptr[n], end = row_ptr[n + 1];
        float2 sd2 = sdP[n];
        float acc0[25] = {}, acc1[25] = {};
        float m0 = -INFINITY, l0 = 0.f, m1 = -INFINITY, l1 = 0.f;
        for (int e = beg; e < end; ++e) {
            unsigned int v = ep[e];
            int s = v & 0x1FFFF;
            int r = v >> 17;
            float2 nd2 = ndP[s];
            float4 rr = rrP[r];           // {rd0, rd1, rw0, rw1}
            float f0[25], f1[25], rv[25];
            if (SRC == 0) {
                const unsigned short* fr = (const unsigned short*)Fin + (size_t)s * FS2;
                const h8* p = (const h8*)(fr + 24 * sb);
                const h8* q = (const h8*)(fr + 104 + 24 * sb);
                h8 x0 = p[0], x1 = p[1], x2 = p[2];
                h8 y0 = q[0], y1 = q[1], y2 = q[2];
#pragma unroll
                for (int m = 0; m < 8; ++m) {
                    f0[m] = h2f(x0.u[m]); f0[8 + m] = h2f(x1.u[m]); f0[16 + m] = h2f(x2.u[m]);
                    f1[m] = h2f(y0.u[m]); f1[8 + m] = h2f(y1.u[m]); f1[16 + m] = h2f(y2.u[m]);
                }
                f0[24] = h2f(fr[96 + sb]);
                f1[24] = h2f(fr[200 + sb]);
            } else {
                const float* fr = (const float*)Fin + (size_t)s * OUTC;
                const float4* a4 = (const float4*)fr;
                const float4* b4 = (const float4*)(fr + 300);
#pragma unroll
                for (int k = 0; k < 6; ++k) {
                    float4 vv = a4[6 * sb + k];
                    f0[4 * k] = vv.x; f0[4 * k + 1] = vv.y; f0[4 * k + 2] = vv.z; f0[4 * k + 3] = vv.w;
                    float4 uu = b4[6 * sb + k];
                    f1[4 * k] = uu.x; f1[4 * k + 1] = uu.y; f1[4 * k + 2] = uu.z; f1[4 * k + 3] = uu.w;
                }
                f0[24] = fr[96 + sb];
                f1[24] = fr[300 + 96 + sb];
            }
            const unsigned short* rh = rel_nh + (size_t)r * HS;
            const h8* rp = (const h8*)(rh + 24 * sb);
            h8 z0 = rp[0], z1 = rp[1], z2 = rp[2];
#pragma unroll
            for (int m = 0; m < 8; ++m) {
                rv[m] = h2f(z0.u[m]); rv[8 + m] = h2f(z1.u[m]); rv[16 + m] = h2f(z2.u[m]);
            }
            rv[24] = h2f(rh[96 + sb]);
            float p0 = f0[24] * rv[24], p1 = f1[24] * rv[24];
#pragma unroll
            for (int m = 0; m < 24; ++m) { p0 += f0[m] * rv[m]; p1 += f1[m] * rv[m]; }
            p0 = quad_sum(p0);
            p1 = quad_sum(p1);
            float c0 = 2.f * p0, c1 = 2.f * p1;
            float lg0 = sd2.x + nd2.x - c0 * rr.z + rr.x;
            float lg1 = sd2.y + nd2.y - c1 * rr.w + rr.y;
            float w0, w1;
            if (lg0 > m0 + RESCALE_THR) {
                float sc = __expf(m0 - lg0);   // 0 on first edge
                l0 *= sc;
#pragma unroll
                for (int m = 0; m < 25; ++m) acc0[m] *= sc;
                m0 = lg0; w0 = 1.f;
            } else w0 = __expf(lg0 - m0);
            if (lg1 > m1 + RESCALE_THR) {
                float sc = __expf(m1 - lg1);
                l1 *= sc;
#pragma unroll
                for (int m = 0; m < 25; ++m) acc1[m] *= sc;
                m1 = lg1; w1 = 1.f;
            } else w1 = __expf(lg1 - m1);
            l0 += w0; l1 += w1;
            float wc0 = w0 * c0, wc1 = w1 * c1;
#pragma unroll
            for (int m = 0; m < 25; ++m) {
                acc0[m] += w0 * f0[m] - wc0 * rv[m];
                acc1[m] += w1 * f1[m] - wc1 * rv[m];
            }
        }
        float i0 = (end > beg) ? (1.f / l0) : 0.f;
        float i1 = (end > beg) ? (1.f / l1) : 0.f;
        float o0[25], o1[25];
#pragma unroll
        for (int m = 0; m < 25; ++m) { o0[m] = tanhf(acc0[m] * i0); o1[m] = tanhf(acc1[m] * i1); }
        if (fused_out) {
            unsigned short* fr = fused_out + (size_t)n * FS2;
#pragma unroll
            for (int j = 0; j < 3; ++j) {
                h8 x, y;
#pragma unroll
                for (int m = 0; m < 8; ++m) { x.u[m] = f2h(o0[8 * j + m]); y.u[m] = f2h(o1[8 * j + m]); }
                ((h8*)(fr + 24 * sb))[j] = x;
                ((h8*)(fr + 104 + 24 * sb))[j] = y;
            }
            fr[96 + sb] = f2h(o0[24]);
            fr[200 + sb] = f2h(o1[24]);
        }
        float* oc = out + (size_t)n * OUTC + ocol;
        float4* oc4 = (float4*)oc;
        float4* od4 = (float4*)(oc + 300);
#pragma unroll
        for (int k = 0; k < 6; ++k) {
            float4 vv = { o0[4 * k], o0[4 * k + 1], o0[4 * k + 2], o0[4 * k + 3] };
            oc4[6 * sb + k] = vv;
            float4 uu = { o1[4 * k], o1[4 * k + 1], o1[4 * k + 2], o1[4 * k + 3] };
            od4[6 * sb + k] = uu;
        }
        oc[96 + sb] = o0[24];
        oc[300 + 96 + sb] = o1[24];
        if (k3dA_next) {
            float sp0 = o0[24] * k3dA_next[96 + sb], np0 = o0[24] * k3dA_next[DD + 96 + sb];
            float sp1 = o1[24] * k3dB_next[96 + sb], np1 = o1[24] * k3dB_next[DD + 96 + sb];
            const float4* wA = (const float4*)k3dA_next;
            const float4* wAn = (const float4*)(k3dA_next + DD);
            const float4* wB = (const float4*)k3dB_next;
            const float4* wBn = (const float4*)(k3dB_next + DD);
#pragma unroll
            for (int k = 0; k < 6; ++k) {
                float4 ws = wA[6 * sb + k], wn = wAn[6 * sb + k];
                sp0 += o0[4 * k] * ws.x + o0[4 * k + 1] * ws.y + o0[4 * k + 2] * ws.z + o0[4 * k + 3] * ws.w;
                np0 += o0[4 * k] * wn.x + o0[4 * k + 1] * wn.y + o0[4 * k + 2] * wn.z + o0[4 * k + 3] * wn.w;
                float4 vs = wB[6 * sb + k], vn = wBn[6 * sb + k];
                sp1 += o1[4 * k] * vs.x + o1[4 * k + 1] * vs.y + o1[4 * k + 2] * vs.z + o1[4 * k + 3] * vs.w;
                np1 += o1[4 * k] * vn.x + o1[4 * k + 1] * vn.y + o1[4 * k + 2] * vn.z + o1[4 * k + 3] * vn.w;
            }
            sp0 = quad_sum(sp0); np0 = quad_sum(np0);
            sp1 = quad_sum(sp1); np1 = quad_sum(np1);
            if (sb == 0) {
                float2 sv = { sp0, sp1 }; sdP_o[n] = sv;
                float2 nv = { np0, np1 }; ndP_o[n] = nv;
            }
        }
    }
}

extern "C" void kernel_launch(void* const* d_in, const int* in_sizes, int n_in,
                              void* d_out, int out_size, void* d_ws, size_t ws_size,
                              hipStream_t stream) {
    const float* ent_emb = (const float*)d_in[0];
    const float* rel_emb = (const float*)d_in[1];
    const float* attn_e  = (const float*)d_in[2];
    const float* attn_r  = (const float*)d_in[3];
    const int*   src     = (const int*)d_in[4];
    const int*   dst     = (const int*)d_in[5];
    const int*   erel    = (const int*)d_in[6];
    float* out = (float*)d_out;

    char* ws = (char*)d_ws;
    auto al = [](size_t x) { return (x + 255) & ~(size_t)255; };
    size_t o = 0;
    auto take = [&](size_t bytes) -> void* { void* p = ws + o; o = al(o + bytes); return p; };

    int*    row_ptr = (int*)take((NN + 1) * sizeof(int));
    unsigned short* rel_nh = (unsigned short*)take((size_t)NR * HS * 2);
    float2* sdPA = (float2*)take(NN * sizeof(float2));
    float2* ndPA = (float2*)take(NN * sizeof(float2));
    float2* sdPB = (float2*)take(NN * sizeof(float2));
    float2* ndPB = (float2*)take(NN * sizeof(float2));
    float4* rrP0 = (float4*)take(NR * sizeof(float4));
    float4* rrP1 = (float4*)take(NR * sizeof(float4));
    int*    ghist = (int*)take(NBIN * sizeof(int));
    int*    goffs = (int*)take(NBIN * sizeof(int));
    int*    perm  = (int*)take(NN * sizeof(int));
    unsigned int* ep = (unsigned int*)take((size_t)NE * 4);

    // Region plan. Lifetimes: {ent_h, rel_eh, rel_norm} die after k_segmean2 /
    // prologue; fusedB is born at L1 → they may alias (plan A).
    size_t tbl0 = o;                                   // ent_h
    size_t tbl1 = al(tbl0 + (size_t)NN * HS * 2);      // rel_eh
    size_t tbl2 = al(tbl1 + (size_t)NR * HS * 2);      // rel_norm (f32)
    size_t tblE = al(tbl2 + (size_t)NR * DD * 4);
    size_t fsz  = al((size_t)NN * FS2 * 2);            // 41.6 MB
    size_t tblSpan = tblE - tbl0;
    size_t fA_A = tbl0 + (fsz > tblSpan ? fsz : tblSpan);
    bool planA = (fA_A + fsz) <= ws_size;              // fusedB aliases tables
    size_t fA_off = planA ? fA_A : tblE;
    bool haveFA = planA || ((tblE + fsz) <= ws_size);

    unsigned short* ent_h  = (unsigned short*)(ws + tbl0);
    unsigned short* rel_eh = (unsigned short*)(ws + tbl1);
    float*          rel_norm = (float*)(ws + tbl2);
    unsigned short* fusedA = haveFA ? (unsigned short*)(ws + fA_off) : (unsigned short*)nullptr;
    unsigned short* fusedB = planA ? (unsigned short*)(ws + tbl0) : (unsigned short*)nullptr;

    hipLaunchKernelGGL(k_rowptr, dim3((NN + 256) / 256), dim3(256), 0, stream,
                       dst, row_ptr, ghist);
    hipLaunchKernelGGL(k_hist, dim3((NN + 255) / 256), dim3(256), 0, stream, row_ptr, ghist);
    hipLaunchKernelGGL(k_scan, dim3(1), dim3(64), 0, stream, ghist, goffs);
    hipLaunchKernelGGL(k_scatter, dim3((NN + 255) / 256), dim3(256), 0, stream,
                       row_ptr, goffs, perm);
    hipLaunchKernelGGL(k_pack, dim3((NE + 255) / 256), dim3(256), 0, stream, src, erel, ep);
    hipLaunchKernelGGL(k_relnorm, dim3(NR * 64 / 256), dim3(256), 0, stream,
                       rel_emb, rel_norm, rel_nh);
    hipLaunchKernelGGL(k_relv2, dim3(NR * 64 / 256), dim3(256), 0, stream,
                       rel_norm, attn_e, attn_r, rrP0);
    hipLaunchKernelGGL(k_relv2, dim3(NR * 64 / 256), dim3(256), 0, stream,
                       rel_norm, attn_e + 300, attn_r + 300, rrP1);
    hipLaunchKernelGGL(k_tohalf, dim3((NN * 4 + 255) / 256), dim3(256), 0, stream,
                       ent_emb, ent_h, NN);
    hipLaunchKernelGGL(k_tohalf, dim3((NR * 4 + 255) / 256), dim3(256), 0, stream,
                       rel_emb, rel_eh, NR);

    // layer 0: fused segment-mean for both encoders (+ layer-0 dots)
    hipLaunchKernelGGL(k_segmean2, dim3(GRID_HEAVY), dim3(256), 0, stream,
                       ent_h, rel_eh, ep, row_ptr, perm,
                       attn_e, attn_r, sdPA, ndPA, fusedA, out);

    // layer 1: writes out cols 100/400 (+ dots for layer 2)
    if (haveFA) {
        hipLaunchKernelGGL(HIP_KERNEL_NAME(k_layer2<0>), dim3(GRID_HEAVY), dim3(256), 0, stream,
                           (const void*)fusedA, rel_nh, ep, row_ptr, perm,
                           sdPA, ndPA, rrP0, attn_e + 300, attn_r + 300,
                           sdPB, ndPB, fusedB, out, 100);
    } else {
        hipLaunchKernelGGL(HIP_KERNEL_NAME(k_layer2<1>), dim3(GRID_HEAVY), dim3(256), 0, stream,
                           (const void*)out, rel_nh, ep, row_ptr, perm,
                           sdPA, ndPA, rrP0, attn_e + 300, attn_r + 300,
                           sdPB, ndPB, (unsigned short*)nullptr, out, 100);
    }

    // layer 2: writes out cols 200/500 (no dots)
    if (planA) {
        hipLaunchKernelGGL(HIP_KERNEL_NAME(k_layer2<0>), dim3(GRID_HEAVY), dim3(256), 0, stream,
                           (const void*)fusedB, rel_nh, ep, row_ptr, perm,
                           sdPB, ndPB, rrP1, (const float*)nullptr, (const float*)nullptr,
                           sdPB, ndPB, (unsigned short*)nullptr, out, 200);
    } else {
        hipLaunchKernelGGL(HIP_KERNEL_NAME(k_layer2<1>), dim3(GRID_HEAVY), dim3(256), 0, stream,
                           (const void*)(out + 100), rel_nh, ep, row_ptr, perm,
                           sdPB, ndPB, rrP1, (const float*)nullptr, (const float*)nullptr,
                           sdPB, ndPB, (unsigned short*)nullptr, out, 200);
    }
}